// Round 3
// baseline (157.746 us; speedup 1.0000x reference)
//
#include <hip/hip_runtime.h>
#include <hip/hip_cooperative_groups.h>

namespace cg = cooperative_groups;

// Problem: A=8, B=16, N=M=1024, K=64. u:(A,B,N,K) f32, v:(A,B,M,K) f32.
// out0 = u * (dot(u_row, v_sum) > 0), out1 = v * (dot(v_row, u_sum) > 0)
//
// Single cooperative kernel, register-resident: each thread loads its
// 8 u-row-slices + 8 v-row-slices ONCE (64 VGPRs), contributes to per-half
// column sums, grid-syncs, then writes masked values from registers.
// HBM traffic: 134 MB read + 134 MB write = the 268 MB floor.

#define NBATCH 128        // A*B
#define NROW   1024       // N == M
#define KDIM   64
#define ELEMS_PER_TENSOR (128ull * 1024ull * 64ull)  // 8388608

// ws layout: float ws[128][2 halves][2 which][64]; which 0 = v colsum, 1 = u colsum
#define WS_OFF(b, h, w) ((((size_t)(b) * 2 + (h)) * 2 + (w)) * KDIM)

__global__ __launch_bounds__(1024, 4)
void fused_kernel(const float* __restrict__ u,
                  const float* __restrict__ v,
                  float* __restrict__ out,
                  float* __restrict__ ws) {
    const int bid   = blockIdx.x;        // 0..255
    const int batch = bid >> 1;          // 0..127
    const int half  = bid & 1;           // rows [half*512, half*512+512)
    const int tid   = threadIdx.x;       // 0..1023
    const int k4    = tid & 15;          // float4 column group
    const int rg    = tid >> 4;          // 0..63 row group

    const size_t base_row = (size_t)batch * NROW + (size_t)half * 512;
    const float4* ub = (const float4*)(u + base_row * KDIM);
    const float4* vb = (const float4*)(v + base_row * KDIM);

    // ---- Phase A: load once into registers, accumulate column partials ----
    float4 ur[8], vr[8];
    float4 su = make_float4(0.f, 0.f, 0.f, 0.f);
    float4 sv = make_float4(0.f, 0.f, 0.f, 0.f);
    #pragma unroll
    for (int i = 0; i < 8; ++i) {
        size_t idx = (size_t)(rg + 64 * i) * 16 + k4;  // 4 rows x 256B per wave: coalesced
        ur[i] = ub[idx];
        vr[i] = vb[idx];
        su.x += ur[i].x; su.y += ur[i].y; su.z += ur[i].z; su.w += ur[i].w;
        sv.x += vr[i].x; sv.y += vr[i].y; sv.z += vr[i].z; sv.w += vr[i].w;
    }

    // LDS reduce 64 row-groups -> half-batch column sums (2-way bank alias: free)
    __shared__ float4 lu[64][16];
    __shared__ float4 lv[64][16];
    lu[rg][k4] = su;
    lv[rg][k4] = sv;
    __syncthreads();

    if (tid < 32) {
        const int which = tid >> 4;      // 0 -> v colsum, 1 -> u colsum
        const int c     = tid & 15;
        float4 t = make_float4(0.f, 0.f, 0.f, 0.f);
        if (which == 0) {
            #pragma unroll
            for (int i = 0; i < 64; ++i) {
                float4 b = lv[i][c];
                t.x += b.x; t.y += b.y; t.z += b.z; t.w += b.w;
            }
        } else {
            #pragma unroll
            for (int i = 0; i < 64; ++i) {
                float4 a = lu[i][c];
                t.x += a.x; t.y += a.y; t.z += a.z; t.w += a.w;
            }
        }
        *(float4*)(ws + WS_OFF(batch, half, which) + c * 4) = t;
    }

    // ---- grid-wide barrier: all halves' partials visible ----
    cg::this_grid().sync();

    // ---- Phase B: fold partials, mask, write from registers ----
    float4 p0 = *(const float4*)(ws + WS_OFF(batch, 0, 0) + k4 * 4);
    float4 p1 = *(const float4*)(ws + WS_OFF(batch, 1, 0) + k4 * 4);
    float4 q0 = *(const float4*)(ws + WS_OFF(batch, 0, 1) + k4 * 4);
    float4 q1 = *(const float4*)(ws + WS_OFF(batch, 1, 1) + k4 * 4);
    float4 vsum = make_float4(p0.x + p1.x, p0.y + p1.y, p0.z + p1.z, p0.w + p1.w);
    float4 usum = make_float4(q0.x + q1.x, q0.y + q1.y, q0.z + q1.z, q0.w + q1.w);

    float4* ou = (float4*)(out + base_row * KDIM);
    float4* ov = (float4*)(out + ELEMS_PER_TENSOR + base_row * KDIM);

    #pragma unroll
    for (int i = 0; i < 8; ++i) {
        size_t idx = (size_t)(rg + 64 * i) * 16 + k4;

        float pu = ur[i].x * vsum.x + ur[i].y * vsum.y + ur[i].z * vsum.z + ur[i].w * vsum.w;
        pu += __shfl_xor(pu, 1);
        pu += __shfl_xor(pu, 2);
        pu += __shfl_xor(pu, 4);
        pu += __shfl_xor(pu, 8);
        float mu = (pu > 0.f) ? 1.f : 0.f;
        ou[idx] = make_float4(ur[i].x * mu, ur[i].y * mu, ur[i].z * mu, ur[i].w * mu);

        float pv = vr[i].x * usum.x + vr[i].y * usum.y + vr[i].z * usum.z + vr[i].w * usum.w;
        pv += __shfl_xor(pv, 1);
        pv += __shfl_xor(pv, 2);
        pv += __shfl_xor(pv, 4);
        pv += __shfl_xor(pv, 8);
        float mv = (pv > 0.f) ? 1.f : 0.f;
        ov[idx] = make_float4(vr[i].x * mv, vr[i].y * mv, vr[i].z * mv, vr[i].w * mv);
    }
}

extern "C" void kernel_launch(void* const* d_in, const int* in_sizes, int n_in,
                              void* d_out, int out_size, void* d_ws, size_t ws_size,
                              hipStream_t stream) {
    const float* u = (const float*)d_in[0];
    const float* v = (const float*)d_in[1];
    float* out = (float*)d_out;
    float* ws  = (float*)d_ws;   // 128*2*2*64 floats = 128 KB, fully overwritten

    void* args[] = {(void*)&u, (void*)&v, (void*)&out, (void*)&ws};
    hipLaunchCooperativeKernel((void*)fused_kernel, dim3(256), dim3(1024),
                               args, 0, stream);
}

// Round 5
// 118.693 us; speedup vs baseline: 1.3290x; 1.3290x over previous
//
#include <hip/hip_runtime.h>

// Problem: A=8, B=16, N=M=1024, K=64. u:(A,B,N,K) f32, v:(A,B,M,K) f32.
// out0 = u * (dot(u_row, v_sum) > 0), out1 = v * (dot(v_row, u_sum) > 0)
//
// ws layout: float ws[128][8 part][2 which][64]
//   which 0 = partial column-sum of v (masks u), 1 = partial column-sum of u
// Fully overwritten by sums_kernel; no memset needed.

#define NBATCH 128        // A*B
#define NROW   1024       // N == M
#define KDIM   64
#define NPART  8
#define ELEMS_PER_TENSOR (128ull * 1024ull * 64ull)  // 8388608

typedef float floatx4 __attribute__((ext_vector_type(4)));  // native vec for nontemporal builtin

// ---------------- Kernel 1: per-batch partial column sums of u and v --------
// grid: 1024 blocks (8 per batch) x 256 threads -> 4 blocks/CU, 16 waves/CU.
__global__ __launch_bounds__(256)
void sums_kernel(const float* __restrict__ u,
                 const float* __restrict__ v,
                 float* __restrict__ sums) {
    int bid    = blockIdx.x;
    int batch  = bid >> 3;            // 0..127
    int part   = bid & 7;
    int rstart = part * 128;          // this block covers 128 rows
    int tid = threadIdx.x;            // 0..255
    int k4  = tid & 15;               // float4 column group
    int rg  = tid >> 4;               // 0..15 row group

    const float4* ub = (const float4*)(u + ((size_t)batch * NROW + rstart) * KDIM);
    const float4* vb = (const float4*)(v + ((size_t)batch * NROW + rstart) * KDIM);

    float4 su = make_float4(0.f, 0.f, 0.f, 0.f);
    float4 sv = make_float4(0.f, 0.f, 0.f, 0.f);
    #pragma unroll
    for (int i = 0; i < 8; ++i) {
        int r = rg + 16 * i;          // 0..127
        float4 a = ub[r * 16 + k4];   // wave covers 4 rows x 256B contiguous
        float4 b = vb[r * 16 + k4];
        su.x += a.x; su.y += a.y; su.z += a.z; su.w += a.w;
        sv.x += b.x; sv.y += b.y; sv.z += b.z; sv.w += b.w;
    }

    __shared__ float4 lu[16][16];
    __shared__ float4 lv[16][16];
    lu[rg][k4] = su;
    lv[rg][k4] = sv;
    __syncthreads();

    if (tid < 32) {
        int which = tid >> 4;         // 0 -> v partial, 1 -> u partial
        int c     = tid & 15;
        float4 t = make_float4(0.f, 0.f, 0.f, 0.f);
        if (which == 0) {
            #pragma unroll
            for (int i = 0; i < 16; ++i) {
                float4 b = lv[i][c];
                t.x += b.x; t.y += b.y; t.z += b.z; t.w += b.w;
            }
        } else {
            #pragma unroll
            for (int i = 0; i < 16; ++i) {
                float4 a = lu[i][c];
                t.x += a.x; t.y += a.y; t.z += a.z; t.w += a.w;
            }
        }
        float* dst = sums + (((size_t)(batch * NPART + part) * 2 + which) * KDIM) + c * 4;
        *(float4*)dst = t;
    }
}

// ---------------- Kernel 2: fold partials + row dot + predicated copy ------
// grid: 16384 blocks x 256 threads. Blocks [0,8192) handle u, rest handle v.
// Each 16-lane subgroup owns one row (64 floats = 16 lanes x float4).
__global__ __launch_bounds__(256)
void mask_kernel(const float* __restrict__ u,
                 const float* __restrict__ v,
                 const float* __restrict__ sums,
                 float* __restrict__ out) {
    int bid  = blockIdx.x;
    int is_v = bid >> 13;             // 0 for u, 1 for v
    int lb   = bid & 8191;            // 64 blocks per batch
    const float* src = is_v ? v : u;
    float* dst = out + (size_t)is_v * ELEMS_PER_TENSOR;

    int batch = lb >> 6;              // 0..127
    int row0  = (lb & 63) * 16;       // 16 rows per block
    int tid   = threadIdx.x;

    // Fold the 8 partials of the sum we need (which == is_v) into LDS once.
    __shared__ float s_lds[KDIM];
    if (tid < KDIM) {
        const float* p0 = sums + ((size_t)(batch * NPART) * 2 + is_v) * KDIM + tid;
        float acc = 0.f;
        #pragma unroll
        for (int p = 0; p < NPART; ++p) acc += p0[p * 2 * KDIM];
        s_lds[tid] = acc;
    }
    __syncthreads();

    int k4 = tid & 15;
    int r  = row0 + (tid >> 4);

    size_t off = ((size_t)batch * NROW + r) * KDIM + (size_t)k4 * 4;
    float4 x   = *(const float4*)(src + off);
    float4 sv4 = *(const float4*)(s_lds + k4 * 4);   // 2-way bank alias: free

    float p = x.x * sv4.x + x.y * sv4.y + x.z * sv4.z + x.w * sv4.w;
    // reduce across the 16 lanes sharing a row (xor masks stay in-group)
    p += __shfl_xor(p, 1);
    p += __shfl_xor(p, 2);
    p += __shfl_xor(p, 4);
    p += __shfl_xor(p, 8);

    float m = (p > 0.f) ? 1.f : 0.f;
    floatx4 o = { x.x * m, x.y * m, x.z * m, x.w * m };
    __builtin_nontemporal_store(o, (floatx4*)(dst + off));  // write-once stream
}

extern "C" void kernel_launch(void* const* d_in, const int* in_sizes, int n_in,
                              void* d_out, int out_size, void* d_ws, size_t ws_size,
                              hipStream_t stream) {
    const float* u = (const float*)d_in[0];
    const float* v = (const float*)d_in[1];
    float* out  = (float*)d_out;
    float* sums = (float*)d_ws;      // 128*8*2*64 floats = 512 KB, fully overwritten

    sums_kernel<<<dim3(1024), dim3(256), 0, stream>>>(u, v, sums);
    mask_kernel<<<dim3(16384), dim3(256), 0, stream>>>(u, v, sums, out);
}

// Round 6
// 117.430 us; speedup vs baseline: 1.3433x; 1.0108x over previous
//
#include <hip/hip_runtime.h>

// Problem: A=8, B=16, N=M=1024, K=64. u:(A,B,N,K) f32, v:(A,B,M,K) f32.
// out0 = u * (dot(u_row, v_sum) > 0), out1 = v * (dot(v_row, u_sum) > 0)
//
// Single kernel, no cross-block sync: block = (batch, half). Each block reads
// the WHOLE batch (1 MB, L3-resident) to compute full-batch column sums
// locally; its own half stays in registers and is masked+written directly.
// Duplicate reads are L3-cheap (round-3 counters: inputs are L3-resident);
// this trades +67 MB L3 reads for: no 2nd global pass, no ws, no 2nd launch.

#define NBATCH 128        // A*B
#define NROW   1024       // N == M
#define KDIM   64
#define ELEMS_PER_TENSOR (128ull * 1024ull * 64ull)  // 8388608

typedef float floatx4 __attribute__((ext_vector_type(4)));  // for nontemporal builtin

__global__ __launch_bounds__(1024)
void fused_local_kernel(const float* __restrict__ u,
                        const float* __restrict__ v,
                        float* __restrict__ out) {
    const int bid   = blockIdx.x;        // 0..255  (== CU count: 1 block/CU)
    const int batch = bid >> 1;          // 0..127
    const int half  = bid & 1;           // own rows: [half*512, half*512+512)
    const int tid   = threadIdx.x;       // 0..1023
    const int k4    = tid & 15;          // float4 column group
    const int rg    = tid >> 4;          // 0..63 row group
    const int wave  = tid >> 6;          // 0..15

    const float4* ub = (const float4*)(u + (size_t)batch * NROW * KDIM);
    const float4* vb = (const float4*)(v + (size_t)batch * NROW * KDIM);

    // ---- Phase A: read full batch; own half -> registers, all -> col sums --
    const int r_own0 = half * 512 + rg;
    const int r_oth0 = (1 - half) * 512 + rg;

    float4 ur[8], vr[8];
    float4 su = make_float4(0.f, 0.f, 0.f, 0.f);   // u colsum partial
    float4 sv = make_float4(0.f, 0.f, 0.f, 0.f);   // v colsum partial
    #pragma unroll
    for (int i = 0; i < 8; ++i) {
        size_t io = (size_t)(r_own0 + 64 * i) * 16 + k4;  // wave: 4 rows x 1KB, coalesced
        ur[i] = ub[io];
        vr[i] = vb[io];
        su.x += ur[i].x; su.y += ur[i].y; su.z += ur[i].z; su.w += ur[i].w;
        sv.x += vr[i].x; sv.y += vr[i].y; sv.z += vr[i].z; sv.w += vr[i].w;
    }
    #pragma unroll
    for (int i = 0; i < 8; ++i) {
        size_t ix = (size_t)(r_oth0 + 64 * i) * 16 + k4;
        float4 a = ub[ix];
        float4 b = vb[ix];
        su.x += a.x; su.y += a.y; su.z += a.z; su.w += a.w;
        sv.x += b.x; sv.y += b.y; sv.z += b.z; sv.w += b.w;
    }

    // ---- Reduce col sums: shfl across the 4 row-groups within each wave ----
    // lanes sharing k4 differ by 16/32 in lane id
    su.x += __shfl_xor(su.x, 16); su.y += __shfl_xor(su.y, 16);
    su.z += __shfl_xor(su.z, 16); su.w += __shfl_xor(su.w, 16);
    su.x += __shfl_xor(su.x, 32); su.y += __shfl_xor(su.y, 32);
    su.z += __shfl_xor(su.z, 32); su.w += __shfl_xor(su.w, 32);
    sv.x += __shfl_xor(sv.x, 16); sv.y += __shfl_xor(sv.y, 16);
    sv.z += __shfl_xor(sv.z, 16); sv.w += __shfl_xor(sv.w, 16);
    sv.x += __shfl_xor(sv.x, 32); sv.y += __shfl_xor(sv.y, 32);
    sv.z += __shfl_xor(sv.z, 32); sv.w += __shfl_xor(sv.w, 32);

    __shared__ float4 red_u[16][16];   // [wave][k4]
    __shared__ float4 red_v[16][16];
    __shared__ float4 fsum[2][16];     // [0]=v colsum (masks u), [1]=u colsum
    if ((tid & 63) < 16) {             // lane 0..15 holds k4 = lane
        red_u[wave][k4] = su;
        red_v[wave][k4] = sv;
    }
    __syncthreads();

    if (tid < 32) {
        const int which = tid >> 4;    // 0 -> v colsum, 1 -> u colsum
        const int c     = tid & 15;
        float4 t = make_float4(0.f, 0.f, 0.f, 0.f);
        if (which == 0) {
            #pragma unroll
            for (int i = 0; i < 16; ++i) {
                float4 b = red_v[i][c];
                t.x += b.x; t.y += b.y; t.z += b.z; t.w += b.w;
            }
        } else {
            #pragma unroll
            for (int i = 0; i < 16; ++i) {
                float4 a = red_u[i][c];
                t.x += a.x; t.y += a.y; t.z += a.z; t.w += a.w;
            }
        }
        fsum[which][c] = t;
    }
    __syncthreads();

    const float4 vs = fsum[0][k4];     // masks u rows
    const float4 us = fsum[1][k4];     // masks v rows

    // ---- Phase B: mask own half from registers, streaming stores ----------
    float* ou = out + (size_t)batch * NROW * KDIM;
    float* ov = out + ELEMS_PER_TENSOR + (size_t)batch * NROW * KDIM;

    #pragma unroll
    for (int i = 0; i < 8; ++i) {
        size_t io = (size_t)(r_own0 + 64 * i) * 16 + k4;

        float pu = ur[i].x * vs.x + ur[i].y * vs.y + ur[i].z * vs.z + ur[i].w * vs.w;
        pu += __shfl_xor(pu, 1);
        pu += __shfl_xor(pu, 2);
        pu += __shfl_xor(pu, 4);
        pu += __shfl_xor(pu, 8);
        float mu = (pu > 0.f) ? 1.f : 0.f;
        floatx4 outu = { ur[i].x * mu, ur[i].y * mu, ur[i].z * mu, ur[i].w * mu };
        __builtin_nontemporal_store(outu, (floatx4*)(ou + io * 4));

        float pv = vr[i].x * us.x + vr[i].y * us.y + vr[i].z * us.z + vr[i].w * us.w;
        pv += __shfl_xor(pv, 1);
        pv += __shfl_xor(pv, 2);
        pv += __shfl_xor(pv, 4);
        pv += __shfl_xor(pv, 8);
        float mv = (pv > 0.f) ? 1.f : 0.f;
        floatx4 outv = { vr[i].x * mv, vr[i].y * mv, vr[i].z * mv, vr[i].w * mv };
        __builtin_nontemporal_store(outv, (floatx4*)(ov + io * 4));
    }
}

extern "C" void kernel_launch(void* const* d_in, const int* in_sizes, int n_in,
                              void* d_out, int out_size, void* d_ws, size_t ws_size,
                              hipStream_t stream) {
    const float* u = (const float*)d_in[0];
    const float* v = (const float*)d_in[1];
    float* out = (float*)d_out;

    fused_local_kernel<<<dim3(256), dim3(1024), 0, stream>>>(u, v, out);
}